// Round 3
// baseline (2986.704 us; speedup 1.0000x reference)
//
#include <hip/hip_runtime.h>
#include <hip/hip_fp16.h>

#define B_ 2048
#define T_ 25
#define CL_ 97

typedef float f32x4 __attribute__((ext_vector_type(4)));
typedef float f32x2 __attribute__((ext_vector_type(2)));
typedef _Float16 f16x8 __attribute__((ext_vector_type(8)));
typedef _Float16 f16x2 __attribute__((ext_vector_type(2)));

#define DI static __device__ __forceinline__

DI float fast_tanh(float x) { return 1.0f - 2.0f / (__expf(2.0f * x) + 1.0f); }
DI float fast_sigm(float x) { return 1.0f / (1.0f + __expf(-x)); }

// async global -> LDS, 16B per lane. LDS dest = wave-uniform base + lane*16.
DI void gl16(const void* g, void* l) {
    __builtin_amdgcn_global_load_lds((const __attribute__((address_space(1))) void*)g,
                                     (__attribute__((address_space(3))) void*)l, 16, 0, 0);
}

// ---------------- pack / convert kernels (run once per call) ----------------

__global__ void k_convx(const float* __restrict__ x, _Float16* __restrict__ xh, int n8) {
    int i = blockIdx.x * 256 + threadIdx.x;
    if (i >= n8) return;
    const f32x4 v0 = *(const f32x4*)(x + (long long)i * 8);
    const f32x4 v1 = *(const f32x4*)(x + (long long)i * 8 + 4);
    f16x8 o;
    o[0] = (_Float16)v0[0]; o[1] = (_Float16)v0[1]; o[2] = (_Float16)v0[2]; o[3] = (_Float16)v0[3];
    o[4] = (_Float16)v1[0]; o[5] = (_Float16)v1[1]; o[6] = (_Float16)v1[2]; o[7] = (_Float16)v1[3];
    *(f16x8*)(xh + (long long)i * 8) = o;
}

__global__ void k_pack_w1(const float* __restrict__ Ws, const float* __restrict__ Whh,
                          const float* __restrict__ Wfc, const float* __restrict__ bs,
                          const float* __restrict__ bhh, const float* __restrict__ bfc,
                          _Float16* __restrict__ w1, float* __restrict__ b1) {
    int idx = blockIdx.x * 256 + threadIdx.x;
    if (idx >= 2 * 2176 * 64) return;
    const int k8 = idx & 63;
    const int n  = (idx >> 6) % 2176;
    const int g  = (idx >> 6) / 2176;
    const int k0 = k8 * 8;
    f16x8 o;
    if (n < 512) {
        const float* p = Ws + (long long)g * 512 * 512 + (long long)k0 * 512 + n;
        #pragma unroll
        for (int i = 0; i < 8; ++i) o[i] = (_Float16)p[(long long)i * 512];
    } else if (n < 2048) {
        const float* p = Whh + (long long)g * 1536 * 512 + (long long)(n - 512) * 512 + k0;
        #pragma unroll
        for (int i = 0; i < 8; ++i) o[i] = (_Float16)p[i];
    } else if (n < 2048 + CL_) {
        const float* p = Wfc + (long long)g * CL_ * 512 + (long long)(n - 2048) * 512 + k0;
        #pragma unroll
        for (int i = 0; i < 8; ++i) o[i] = (_Float16)p[i];
    } else {
        #pragma unroll
        for (int i = 0; i < 8; ++i) o[i] = (_Float16)0.0f;
    }
    *(f16x8*)(w1 + ((long long)g * 2176 + n) * 512 + k0) = o;
    if (k8 == 0) {
        float bv = (n < 512) ? bs[g * 512 + n]
                 : (n < 2048) ? bhh[g * 1536 + (n - 512)]
                 : (n < 2048 + CL_) ? bfc[g * CL_ + (n - 2048)] : 0.0f;
        b1[g * 2176 + n] = bv;
    }
}

__global__ void k_pack_w2(const float* __restrict__ Wih, _Float16* __restrict__ w2,
                          _Float16* __restrict__ w2e) {
    int idx = blockIdx.x * 256 + threadIdx.x;
    if (idx >= 2 * 1536 * 64) return;
    const int k8 = idx & 63;
    const int n  = (idx >> 6) % 1536;
    const int g  = (idx >> 6) / 1536;
    const int k0 = k8 * 8;
    const float* p = Wih + (long long)g * 1536 * 1024 + (long long)n * 1024;
    f16x8 o, oe;
    #pragma unroll
    for (int i = 0; i < 8; ++i) { o[i] = (_Float16)p[512 + k0 + i]; oe[i] = (_Float16)p[k0 + i]; }
    *(f16x8*)(w2  + ((long long)g * 1536 + n) * 512 + k0) = o;
    *(f16x8*)(w2e + ((long long)g * 1536 + n) * 512 + k0) = oe;
}

__global__ void k_pack_wx(const float* __restrict__ Wx, _Float16* __restrict__ wx) {
    int idx = blockIdx.x * 256 + threadIdx.x;
    if (idx >= 2 * 512 * 64) return;
    const int k8 = idx & 63;
    const int n  = (idx >> 6) & 511;
    const int g  = (idx >> 6) >> 9;
    const int k0 = k8 * 8;
    const float* p = Wx + (long long)g * 512 * 512 + (long long)k0 * 512 + n;
    f16x8 o;
    #pragma unroll
    for (int i = 0; i < 8; ++i) o[i] = (_Float16)p[(long long)i * 512];
    *(f16x8*)(wx + ((long long)g * 512 + n) * 512 + k0) = o;
}

__global__ void k_pack_emb(const float* __restrict__ emb, _Float16* __restrict__ embh) {
    int i = blockIdx.x * 256 + threadIdx.x;
    if (i >= 2 * 128 * 64) return;
    const int k8 = i & 63;
    const int y  = (i >> 6) & 127;
    const int g  = i >> 13;
    f16x8 o;
    if (y < 98) {
        const float* p = emb + (long long)(g * 98 + y) * 512 + k8 * 8;
        #pragma unroll
        for (int j = 0; j < 8; ++j) o[j] = (_Float16)p[j];
    } else {
        #pragma unroll
        for (int j = 0; j < 8; ++j) o[j] = (_Float16)0.0f;
    }
    *(f16x8*)(embh + (long long)(g * 128 + y) * 512 + k8 * 8) = o;
}

// ---------------- GEMM: C[M][N] = A[M][512] * B^T[N][512] (+bias) ----------------
// 128x128 tile, BK=64, 4 waves (2x2), 16x16x32 f16 MFMA, f32 accum.
// 2-deep prefetch (T3-min): STAGE(next) issued before compute(cur), counted
// s_waitcnt vmcnt(8) + raw s_barrier keeps next tile's 8 loads/wave in flight
// under the MFMAs. T2 swizzle: slot ^= row&7 at 16B granularity, applied as
// inverse-swizzled GLOBAL source (gl16 dest stays linear, G21) + swizzled ds_read.
__global__ __launch_bounds__(256) void gemm_bt(
    const _Float16* __restrict__ A, long long aG,
    const _Float16* __restrict__ B, long long bG,
    float* __restrict__ Cf, _Float16* __restrict__ Ch,
    long long cG, int ldc,
    const float* __restrict__ bias, int biasG,
    int nblk_off, int n_split,
    float* __restrict__ lout, int lcols, int lldc)
{
    __shared__ _Float16 As[2][128 * 64];
    __shared__ _Float16 Bs[2][128 * 64];
    const int g  = blockIdx.z;
    const int m0 = blockIdx.y * 128;
    const int n0 = (blockIdx.x + nblk_off) * 128;
    const _Float16* Ag = A + (long long)g * aG + (long long)m0 * 512;
    const _Float16* Bg = B + (long long)g * bG + (long long)n0 * 512;
    const int tid  = threadIdx.x;
    const int lane = tid & 63, w = tid >> 6;
    const int wr = w >> 1, wc = w & 1;
    const int lr = lane & 15, kg = lane >> 4;
    const int srow = lane >> 3;                         // 0..7 within 8-row chunk
    const int scol = (((lane & 7) ^ srow) * 8);         // inverse-swizzled source col

    f32x4 acc[4][4];
    #pragma unroll
    for (int m = 0; m < 4; ++m)
        #pragma unroll
        for (int n = 0; n < 4; ++n) acc[m][n] = (f32x4)0.0f;

    // stage one K-tile (8 gl16 per wave: 4 row-chunks x {A,B})
    auto stage = [&](int buf, int kt) {
        const int k0 = kt * 64;
        #pragma unroll
        for (int cc = 0; cc < 4; ++cc) {
            const int r = w * 32 + cc * 8;
            gl16(Ag + (long long)(r + srow) * 512 + k0 + scol, &As[buf][r * 64]);
            gl16(Bg + (long long)(r + srow) * 512 + k0 + scol, &Bs[buf][r * 64]);
        }
    };

    stage(0, 0);
    #pragma unroll
    for (int kt = 0; kt < 8; ++kt) {
        const int cur = kt & 1;
        if (kt < 7) {
            stage(cur ^ 1, kt + 1);                     // 16 outstanding after this
            asm volatile("s_waitcnt vmcnt(8)" ::: "memory");   // cur tile's 8 done
        } else {
            asm volatile("s_waitcnt vmcnt(0)" ::: "memory");
        }
        __builtin_amdgcn_s_barrier();                   // cur tile visible to all
        #pragma unroll
        for (int kk = 0; kk < 2; ++kk) {
            f16x8 af[4], bf[4];
            #pragma unroll
            for (int m = 0; m < 4; ++m) {
                const int R = wr * 64 + m * 16 + lr;
                af[m] = *(const f16x8*)&As[cur][R * 64 + (((kk * 4 + kg) ^ (R & 7)) * 8)];
            }
            #pragma unroll
            for (int n = 0; n < 4; ++n) {
                const int R = wc * 64 + n * 16 + lr;
                bf[n] = *(const f16x8*)&Bs[cur][R * 64 + (((kk * 4 + kg) ^ (R & 7)) * 8)];
            }
            #pragma unroll
            for (int m = 0; m < 4; ++m)
                #pragma unroll
                for (int n = 0; n < 4; ++n)
                    acc[m][n] = __builtin_amdgcn_mfma_f32_16x16x32_f16(af[m], bf[n], acc[m][n], 0, 0, 0);
        }
        __builtin_amdgcn_s_barrier();                   // reads done before overwrite
    }

    // epilogue: D frag mapping col = lane&15, row = (lane>>4)*4 + i  (m89-verified)
    #pragma unroll
    for (int n = 0; n < 4; ++n) {
        const int col = n0 + wc * 64 + n * 16 + lr;
        const float bb = bias ? bias[g * biasG + col] : 0.0f;
        if (col < n_split) {
            #pragma unroll
            for (int m = 0; m < 4; ++m) {
                const int row = m0 + wr * 64 + m * 16 + kg * 4;
                #pragma unroll
                for (int i = 0; i < 4; ++i) {
                    const long long off = (long long)g * cG + (long long)(row + i) * ldc + col;
                    const float v = acc[m][n][i] + bb;
                    if (Ch) Ch[off] = (_Float16)v; else Cf[off] = v;
                }
            }
        } else if (lout != nullptr) {
            const int c = col - n_split;
            if (c < lcols) {
                #pragma unroll
                for (int m = 0; m < 4; ++m) {
                    const int row = m0 + wr * 64 + m * 16 + kg * 4;
                    #pragma unroll
                    for (int i = 0; i < 4; ++i)
                        lout[(long long)(g * B_ + row + i) * lldc + c] = acc[m][n][i] + bb;
                }
            }
        }
    }
}

// ---------------- fused attention, both decoders per block ----------------
// e = tanh(sProj+xProj)·wv, softmax over L=25, ctx = sum_l alpha_l x_l.
// Wave w owns rows {l : l%4==w}; all loads 16B/lane; xh read ONCE for both g.
__global__ __launch_bounds__(256) void k_att(
    const _Float16* __restrict__ Yh,    // [2][B][2048]; sProj = cols 0..511
    const _Float16* __restrict__ xpj,   // [2][B][25][512]
    const _Float16* __restrict__ xh,    // [B][25][512]
    const float* __restrict__ wv,       // [2][512]
    _Float16* __restrict__ ctxh)        // [2][B][512]
{
    const int b = blockIdx.x;
    const int tid = threadIdx.x, lane = tid & 63, w = tid >> 6;
    __shared__ float eL[2][28];
    __shared__ float red[2][4][512];    // 16 KB partial-sum buffer
    const int a0 = lane * 8;

    // phase 1: attention energies for both g
    #pragma unroll
    for (int g = 0; g < 2; ++g) {
        const _Float16* sp = Yh + (long long)(g * B_ + b) * 2048;
        const f16x8 spv = *(const f16x8*)(sp + a0);
        const float* wvg = wv + g * 512;
        const f32x4 wv0 = *(const f32x4*)(wvg + a0);
        const f32x4 wv1 = *(const f32x4*)(wvg + a0 + 4);
        const _Float16* xpb = xpj + (long long)(g * B_ + b) * 25 * 512;
        for (int l = w; l < 25; l += 4) {
            const f16x8 xv = *(const f16x8*)(xpb + l * 512 + a0);
            float part = 0.0f;
            #pragma unroll
            for (int i = 0; i < 4; ++i) {
                part += fast_tanh((float)spv[i]     + (float)xv[i])     * wv0[i];
                part += fast_tanh((float)spv[4 + i] + (float)xv[4 + i]) * wv1[i];
            }
            #pragma unroll
            for (int off = 32; off > 0; off >>= 1) part += __shfl_xor(part, off);
            if (lane == 0) eL[g][l] = part;     // wvb cancels in softmax
        }
    }
    __syncthreads();

    // phase 2: per-thread softmax weights (statically indexed arrays)
    float al0[25], al1[25];
    float m0 = -1e30f, m1 = -1e30f;
    #pragma unroll
    for (int l = 0; l < 25; ++l) { m0 = fmaxf(m0, eL[0][l]); m1 = fmaxf(m1, eL[1][l]); }
    float ss0 = 0.0f, ss1 = 0.0f;
    #pragma unroll
    for (int l = 0; l < 25; ++l) {
        al0[l] = __expf(eL[0][l] - m0); ss0 += al0[l];
        al1[l] = __expf(eL[1][l] - m1); ss1 += al1[l];
    }
    const float inv0 = 1.0f / ss0, inv1 = 1.0f / ss1;

    // phase 3: ctx partials; wave w accumulates its rows over full 512 cols
    float c0[8], c1[8];
    #pragma unroll
    for (int j = 0; j < 8; ++j) { c0[j] = 0.0f; c1[j] = 0.0f; }
    const _Float16* xb = xh + (long long)b * 25 * 512;
    #pragma unroll
    for (int l = 0; l < 25; ++l) {
        if ((l & 3) == w) {                    // wave-uniform guard, l stays static
            const f16x8 xv = *(const f16x8*)(xb + l * 512 + a0);
            #pragma unroll
            for (int j = 0; j < 8; ++j) {
                const float xf = (float)xv[j];
                c0[j] += al0[l] * xf;
                c1[j] += al1[l] * xf;
            }
        }
    }
    f32x4 p;
    #pragma unroll
    for (int h = 0; h < 2; ++h) {
        #pragma unroll
        for (int i = 0; i < 4; ++i) p[i] = c0[h * 4 + i] * inv0;
        *(f32x4*)&red[0][w][a0 + h * 4] = p;
        #pragma unroll
        for (int i = 0; i < 4; ++i) p[i] = c1[h * 4 + i] * inv1;
        *(f32x4*)&red[1][w][a0 + h * 4] = p;
    }
    __syncthreads();

    // phase 4: cross-wave reduce + fp16 store, 2 cols/thread per g
    const int c = tid * 2;
    f32x2 s0 = {0.0f, 0.0f}, s1 = {0.0f, 0.0f};
    #pragma unroll
    for (int ww = 0; ww < 4; ++ww) {
        s0 += *(const f32x2*)&red[0][ww][c];
        s1 += *(const f32x2*)&red[1][ww][c];
    }
    f16x2 o0, o1;
    o0[0] = (_Float16)s0[0]; o0[1] = (_Float16)s0[1];
    o1[0] = (_Float16)s1[0]; o1[1] = (_Float16)s1[1];
    *(f16x2*)(ctxh + (long long)b * 512 + c) = o0;
    *(f16x2*)(ctxh + (long long)(B_ + b) * 512 + c) = o1;
}

// ---------------- GRU gate + state update (2 cols per thread) ----------------
__global__ void k_gate(const _Float16* __restrict__ Yh,  // gh = cols 512..2047
                       const _Float16* __restrict__ Y2h, // ctxProj [2][B][1536]
                       const float* __restrict__ eW,     // embW [2][128][1536] (incl bih)
                       const int* __restrict__ tgt,      // [2][B][25]
                       float* __restrict__ s32, _Float16* __restrict__ sh, int t)
{
    const int idx = blockIdx.x * 256 + threadIdx.x;
    if (idx >= 2 * B_ * 256) return;
    const int jp = (idx & 255) * 2;
    const int b  = (idx >> 8) & (B_ - 1);
    const int g  = idx >> 19;
    const int y  = (t == 0) ? CL_ : tgt[(g * B_ + b) * T_ + t - 1];
    const float*    ew = eW  + (long long)(g * 128 + y) * 1536;
    const _Float16* y2 = Y2h + (long long)(g * B_ + b) * 1536;
    const _Float16* yy = Yh  + (long long)(g * B_ + b) * 2048;
    const f32x2 ewr = *(const f32x2*)(ew + jp);
    const f32x2 ewz = *(const f32x2*)(ew + 512 + jp);
    const f32x2 ewn = *(const f32x2*)(ew + 1024 + jp);
    const f16x2 y2r = *(const f16x2*)(y2 + jp);
    const f16x2 y2z = *(const f16x2*)(y2 + 512 + jp);
    const f16x2 y2n = *(const f16x2*)(y2 + 1024 + jp);
    const f16x2 ghr = *(const f16x2*)(yy + 512 + jp);
    const f16x2 ghz = *(const f16x2*)(yy + 1024 + jp);
    const f16x2 ghn = *(const f16x2*)(yy + 1536 + jp);
    const long long si = (long long)(g * B_ + b) * 512 + jp;
    const f32x2 so = *(const f32x2*)(s32 + si);
    f32x2 sn;
    f16x2 snh;
    #pragma unroll
    for (int i = 0; i < 2; ++i) {
        const float r  = fast_sigm(ewr[i] + (float)y2r[i] + (float)ghr[i]);
        const float z  = fast_sigm(ewz[i] + (float)y2z[i] + (float)ghz[i]);
        const float nn = fast_tanh(ewn[i] + (float)y2n[i] + r * (float)ghn[i]);
        sn[i]  = (1.0f - z) * nn + z * so[i];
        snh[i] = (_Float16)sn[i];
    }
    *(f32x2*)(s32 + si) = sn;
    *(f16x2*)(sh + si) = snh;
}

// ---------------- launcher ----------------
extern "C" void kernel_launch(void* const* d_in, const int* in_sizes, int n_in,
                              void* d_out, int out_size, void* d_ws, size_t ws_size,
                              hipStream_t stream)
{
    (void)in_sizes; (void)n_in; (void)out_size;
    const float* x   = (const float*)d_in[0];
    const int*   tgt = (const int*)d_in[1];
    const float* Wx  = (const float*)d_in[2];
    const float* bx  = (const float*)d_in[3];
    const float* Wsm = (const float*)d_in[4];
    const float* bs  = (const float*)d_in[5];
    const float* wv  = (const float*)d_in[6];
    // d_in[7] = wvb: cancels in softmax, unused
    const float* emb = (const float*)d_in[8];
    const float* Wih = (const float*)d_in[9];
    const float* bih = (const float*)d_in[10];
    const float* Whh = (const float*)d_in[11];
    const float* bhh = (const float*)d_in[12];
    const float* Wfc = (const float*)d_in[13];
    const float* bfc = (const float*)d_in[14];
    float* out = (float*)d_out;

    char* base = (char*)d_ws;
    size_t off = 0;
    auto alloc = [&](size_t bytes) -> void* {
        void* r = base + off;
        off = (off + bytes + 255) & ~(size_t)255;
        return r;
    };
    _Float16* xh   = (_Float16*)alloc((size_t)B_ * T_ * 512 * 2);
    _Float16* xpj  = (_Float16*)alloc((size_t)2 * B_ * T_ * 512 * 2);
    _Float16* w1   = (_Float16*)alloc((size_t)2 * 2176 * 512 * 2);
    _Float16* w2   = (_Float16*)alloc((size_t)2 * 1536 * 512 * 2);
    _Float16* w2e  = (_Float16*)alloc((size_t)2 * 1536 * 512 * 2);
    _Float16* wx   = (_Float16*)alloc((size_t)2 * 512 * 512 * 2);
    _Float16* embh = (_Float16*)alloc((size_t)2 * 128 * 512 * 2);
    float*    b1   = (float*)alloc((size_t)2 * 2176 * 4);
    float*    eW   = (float*)alloc((size_t)2 * 128 * 1536 * 4);
    float*    s32  = (float*)alloc((size_t)2 * B_ * 512 * 4);
    _Float16* sh   = (_Float16*)alloc((size_t)2 * B_ * 512 * 2);
    _Float16* ctx  = (_Float16*)alloc((size_t)2 * B_ * 512 * 2);
    _Float16* Yh   = (_Float16*)alloc((size_t)2 * B_ * 2048 * 2);
    _Float16* Y2h  = (_Float16*)alloc((size_t)2 * B_ * 1536 * 2);
    if (off > ws_size) return;

    hipMemsetAsync(s32, 0, (size_t)2 * B_ * 512 * 4, stream);
    hipMemsetAsync(sh,  0, (size_t)2 * B_ * 512 * 2, stream);

    k_convx   <<<12800, 256, 0, stream>>>(x, xh, (B_ * T_ * 512) / 8);
    k_pack_w1 <<<1088, 256, 0, stream>>>(Wsm, Whh, Wfc, bs, bhh, bfc, w1, b1);
    k_pack_w2 <<<768, 256, 0, stream>>>(Wih, w2, w2e);
    k_pack_wx <<<256, 256, 0, stream>>>(Wx, wx);
    k_pack_emb<<<64, 256, 0, stream>>>(emb, embh);

    // embW = embh @ w2e^T + bih : M=128, N=1536
    gemm_bt<<<dim3(12, 1, 2), 256, 0, stream>>>(
        embh, 128ll * 512, w2e, 1536ll * 512, eW, nullptr,
        128ll * 1536, 1536, bih, 1536, 0, 1 << 30, nullptr, 0, 0);

    // xProj[g] = xh @ WxBt[g] + bx[g]  (fp16 out), M=51200, N=512
    gemm_bt<<<dim3(4, 400, 2), 256, 0, stream>>>(
        xh, 0ll, wx, 512ll * 512, nullptr, xpj, (long long)B_ * T_ * 512, 512,
        bx, 512, 0, 1 << 30, nullptr, 0, 0);

    for (int t = 0; t < T_; ++t) {
        // Y = s @ [Ws | Whh.T | Wfc.T] + [bs|bhh|bfc]; logits cols -> out[t-1]
        gemm_bt<<<dim3(t > 0 ? 17 : 16, 16, 2), 256, 0, stream>>>(
            sh, (long long)B_ * 512, w1, 2176ll * 512, nullptr, Yh,
            (long long)B_ * 2048, 2048, b1, 2176, 0, 2048,
            t > 0 ? out + (long long)(t - 1) * CL_ : nullptr, CL_, T_ * CL_);
        k_att<<<dim3(B_, 1, 1), 256, 0, stream>>>(Yh, xpj, xh, wv, ctx);
        // ctxProj = ctx @ WihCtx.T  (bih folded into embW)
        gemm_bt<<<dim3(12, 16, 2), 256, 0, stream>>>(
            ctx, (long long)B_ * 512, w2, 1536ll * 512, nullptr, Y2h,
            (long long)B_ * 1536, 1536, nullptr, 0, 0, 1 << 30, nullptr, 0, 0);
        k_gate<<<4096, 256, 0, stream>>>(Yh, Y2h, eW, tgt, s32, sh, t);
    }
    // final logits (step T-1) from s_T
    gemm_bt<<<dim3(1, 16, 2), 256, 0, stream>>>(
        sh, (long long)B_ * 512, w1, 2176ll * 512, nullptr, Yh,
        (long long)B_ * 2048, 2048, b1, 2176, 16, 2048,
        out + 24ll * CL_, CL_, T_ * CL_);
}

// Round 4
// 2674.977 us; speedup vs baseline: 1.1165x; 1.1165x over previous
//
#include <hip/hip_runtime.h>
#include <hip/hip_fp16.h>

#define B_ 2048
#define T_ 25
#define CL_ 97

typedef float f32x4 __attribute__((ext_vector_type(4)));
typedef float f32x2 __attribute__((ext_vector_type(2)));
typedef _Float16 f16x8 __attribute__((ext_vector_type(8)));
typedef _Float16 f16x2 __attribute__((ext_vector_type(2)));

#define DI static __device__ __forceinline__

DI float fast_tanh(float x) { return 1.0f - 2.0f / (__expf(2.0f * x) + 1.0f); }
DI float fast_sigm(float x) { return 1.0f / (1.0f + __expf(-x)); }

// async global -> LDS, 16B per lane. LDS dest = wave-uniform base + lane*16.
DI void gl16(const void* g, void* l) {
    __builtin_amdgcn_global_load_lds((const __attribute__((address_space(1))) void*)g,
                                     (__attribute__((address_space(3))) void*)l, 16, 0, 0);
}

// ---------------- pack / convert kernels (run once per call) ----------------

__global__ void k_convx(const float* __restrict__ x, _Float16* __restrict__ xh, int n8) {
    int i = blockIdx.x * 256 + threadIdx.x;
    if (i >= n8) return;
    const f32x4 v0 = *(const f32x4*)(x + (long long)i * 8);
    const f32x4 v1 = *(const f32x4*)(x + (long long)i * 8 + 4);
    f16x8 o;
    o[0] = (_Float16)v0[0]; o[1] = (_Float16)v0[1]; o[2] = (_Float16)v0[2]; o[3] = (_Float16)v0[3];
    o[4] = (_Float16)v1[0]; o[5] = (_Float16)v1[1]; o[6] = (_Float16)v1[2]; o[7] = (_Float16)v1[3];
    *(f16x8*)(xh + (long long)i * 8) = o;
}

__global__ void k_pack_w1(const float* __restrict__ Ws, const float* __restrict__ Whh,
                          const float* __restrict__ Wfc, const float* __restrict__ bs,
                          const float* __restrict__ bhh, const float* __restrict__ bfc,
                          _Float16* __restrict__ w1, float* __restrict__ b1) {
    int idx = blockIdx.x * 256 + threadIdx.x;
    if (idx >= 2 * 2176 * 64) return;
    const int k8 = idx & 63;
    const int n  = (idx >> 6) % 2176;
    const int g  = (idx >> 6) / 2176;
    const int k0 = k8 * 8;
    f16x8 o;
    if (n < 512) {
        const float* p = Ws + (long long)g * 512 * 512 + (long long)k0 * 512 + n;
        #pragma unroll
        for (int i = 0; i < 8; ++i) o[i] = (_Float16)p[(long long)i * 512];
    } else if (n < 2048) {
        const float* p = Whh + (long long)g * 1536 * 512 + (long long)(n - 512) * 512 + k0;
        #pragma unroll
        for (int i = 0; i < 8; ++i) o[i] = (_Float16)p[i];
    } else if (n < 2048 + CL_) {
        const float* p = Wfc + (long long)g * CL_ * 512 + (long long)(n - 2048) * 512 + k0;
        #pragma unroll
        for (int i = 0; i < 8; ++i) o[i] = (_Float16)p[i];
    } else {
        #pragma unroll
        for (int i = 0; i < 8; ++i) o[i] = (_Float16)0.0f;
    }
    *(f16x8*)(w1 + ((long long)g * 2176 + n) * 512 + k0) = o;
    if (k8 == 0) {
        float bv = (n < 512) ? bs[g * 512 + n]
                 : (n < 2048) ? bhh[g * 1536 + (n - 512)]
                 : (n < 2048 + CL_) ? bfc[g * CL_ + (n - 2048)] : 0.0f;
        b1[g * 2176 + n] = bv;
    }
}

__global__ void k_pack_w2(const float* __restrict__ Wih, _Float16* __restrict__ w2,
                          _Float16* __restrict__ w2e) {
    int idx = blockIdx.x * 256 + threadIdx.x;
    if (idx >= 2 * 1536 * 64) return;
    const int k8 = idx & 63;
    const int n  = (idx >> 6) % 1536;
    const int g  = (idx >> 6) / 1536;
    const int k0 = k8 * 8;
    const float* p = Wih + (long long)g * 1536 * 1024 + (long long)n * 1024;
    f16x8 o, oe;
    #pragma unroll
    for (int i = 0; i < 8; ++i) { o[i] = (_Float16)p[512 + k0 + i]; oe[i] = (_Float16)p[k0 + i]; }
    *(f16x8*)(w2  + ((long long)g * 1536 + n) * 512 + k0) = o;
    *(f16x8*)(w2e + ((long long)g * 1536 + n) * 512 + k0) = oe;
}

__global__ void k_pack_wx(const float* __restrict__ Wx, _Float16* __restrict__ wx) {
    int idx = blockIdx.x * 256 + threadIdx.x;
    if (idx >= 2 * 512 * 64) return;
    const int k8 = idx & 63;
    const int n  = (idx >> 6) & 511;
    const int g  = (idx >> 6) >> 9;
    const int k0 = k8 * 8;
    const float* p = Wx + (long long)g * 512 * 512 + (long long)k0 * 512 + n;
    f16x8 o;
    #pragma unroll
    for (int i = 0; i < 8; ++i) o[i] = (_Float16)p[(long long)i * 512];
    *(f16x8*)(wx + ((long long)g * 512 + n) * 512 + k0) = o;
}

__global__ void k_pack_emb(const float* __restrict__ emb, _Float16* __restrict__ embh) {
    int i = blockIdx.x * 256 + threadIdx.x;
    if (i >= 2 * 128 * 64) return;
    const int k8 = i & 63;
    const int y  = (i >> 6) & 127;
    const int g  = i >> 13;
    f16x8 o;
    if (y < 98) {
        const float* p = emb + (long long)(g * 98 + y) * 512 + k8 * 8;
        #pragma unroll
        for (int j = 0; j < 8; ++j) o[j] = (_Float16)p[j];
    } else {
        #pragma unroll
        for (int j = 0; j < 8; ++j) o[j] = (_Float16)0.0f;
    }
    *(f16x8*)(embh + (long long)(g * 128 + y) * 512 + k8 * 8) = o;
}

// ---------------- GEMM: C[M][N] = A[M][512] * B^T[N][512] (+bias) ----------------
// 128x128 tile, BK=64, 4 waves (2x2), 16x16x32 f16 MFMA, f32 accum.
// m97 structure: SINGLE 32KB LDS buffer (5 blocks/CU -> TLP hides the per-tile
// drain, m114) + verified T2 swizzle (inverse-swizzled global source, G21;
// ds_read slot ^ (row&7) -> 2 lanes/16B-slot = conflict-free, measured 0 in R3).
// T1: bijective XCD remap (m204) of the (x,y) grid, bx-fastest for L2 reuse.
__global__ __launch_bounds__(256) void gemm_bt(
    const _Float16* __restrict__ A, long long aG,
    const _Float16* __restrict__ B, long long bG,
    float* __restrict__ Cf, _Float16* __restrict__ Ch,
    long long cG, int ldc,
    const float* __restrict__ bias, int biasG,
    int nblk_off, int n_split,
    float* __restrict__ lout, int lcols, int lldc)
{
    __shared__ _Float16 As[128 * 64];
    __shared__ _Float16 Bs[128 * 64];
    // XCD-aware bijective remap (m204): dispatch o lands on XCD o%8; give each
    // XCD a contiguous chunk of tile space (bx fastest -> shared A-panel).
    const int gx = gridDim.x, nwg = gx * gridDim.y;
    const int o = blockIdx.y * gx + blockIdx.x;
    const int q = nwg >> 3, r = nwg & 7;
    const int xcd = o & 7, ii = o >> 3;
    const int nn = (xcd < r ? xcd * (q + 1) : r * (q + 1) + (xcd - r) * q) + ii;
    const int bx = nn % gx, by = nn / gx;

    const int g  = blockIdx.z;
    const int m0 = by * 128;
    const int n0 = (bx + nblk_off) * 128;
    const _Float16* Ag = A + (long long)g * aG + (long long)m0 * 512;
    const _Float16* Bg = B + (long long)g * bG + (long long)n0 * 512;
    const int tid  = threadIdx.x;
    const int lane = tid & 63, w = tid >> 6;
    const int wr = w >> 1, wc = w & 1;
    const int lr = lane & 15, kg = lane >> 4;
    const int srow = lane >> 3;                         // 0..7 within 8-row chunk
    const int scol = (((lane & 7) ^ srow) * 8);         // inverse-swizzled source col

    f32x4 acc[4][4];
    #pragma unroll
    for (int m = 0; m < 4; ++m)
        #pragma unroll
        for (int n = 0; n < 4; ++n) acc[m][n] = (f32x4)0.0f;

    #pragma unroll
    for (int kt = 0; kt < 8; ++kt) {
        const int k0 = kt * 64;
        __syncthreads();   // all waves done reading previous tile
        #pragma unroll
        for (int cc = 0; cc < 4; ++cc) {
            const int rr = w * 32 + cc * 8;
            gl16(Ag + (long long)(rr + srow) * 512 + k0 + scol, &As[rr * 64]);
            gl16(Bg + (long long)(rr + srow) * 512 + k0 + scol, &Bs[rr * 64]);
        }
        __syncthreads();   // compiler drains vmcnt(0) -> tile visible
        #pragma unroll
        for (int kk = 0; kk < 2; ++kk) {
            f16x8 af[4], bf[4];
            #pragma unroll
            for (int m = 0; m < 4; ++m) {
                const int R = wr * 64 + m * 16 + lr;
                af[m] = *(const f16x8*)&As[R * 64 + (((kk * 4 + kg) ^ (R & 7)) * 8)];
            }
            #pragma unroll
            for (int n = 0; n < 4; ++n) {
                const int R = wc * 64 + n * 16 + lr;
                bf[n] = *(const f16x8*)&Bs[R * 64 + (((kk * 4 + kg) ^ (R & 7)) * 8)];
            }
            #pragma unroll
            for (int m = 0; m < 4; ++m)
                #pragma unroll
                for (int n = 0; n < 4; ++n)
                    acc[m][n] = __builtin_amdgcn_mfma_f32_16x16x32_f16(af[m], bf[n], acc[m][n], 0, 0, 0);
        }
    }

    // epilogue: D frag mapping col = lane&15, row = (lane>>4)*4 + i  (m89-verified)
    #pragma unroll
    for (int n = 0; n < 4; ++n) {
        const int col = n0 + wc * 64 + n * 16 + lr;
        const float bb = bias ? bias[g * biasG + col] : 0.0f;
        if (col < n_split) {
            #pragma unroll
            for (int m = 0; m < 4; ++m) {
                const int row = m0 + wr * 64 + m * 16 + kg * 4;
                #pragma unroll
                for (int i = 0; i < 4; ++i) {
                    const long long off = (long long)g * cG + (long long)(row + i) * ldc + col;
                    const float v = acc[m][n][i] + bb;
                    if (Ch) Ch[off] = (_Float16)v; else Cf[off] = v;
                }
            }
        } else if (lout != nullptr) {
            const int c = col - n_split;
            if (c < lcols) {
                #pragma unroll
                for (int m = 0; m < 4; ++m) {
                    const int row = m0 + wr * 64 + m * 16 + kg * 4;
                    #pragma unroll
                    for (int i = 0; i < 4; ++i)
                        lout[(long long)(g * B_ + row + i) * lldc + c] = acc[m][n][i] + bb;
                }
            }
        }
    }
}

// ---------------- fused attention, both decoders per block ----------------
__global__ __launch_bounds__(256) void k_att(
    const _Float16* __restrict__ Yh,    // [2][B][2048]; sProj = cols 0..511
    const _Float16* __restrict__ xpj,   // [2][B][25][512]
    const _Float16* __restrict__ xh,    // [B][25][512]
    const float* __restrict__ wv,       // [2][512]
    _Float16* __restrict__ ctxh)        // [2][B][512]
{
    const int b = blockIdx.x;
    const int tid = threadIdx.x, lane = tid & 63, w = tid >> 6;
    __shared__ float eL[2][28];
    __shared__ float red[2][4][512];    // 16 KB partial-sum buffer
    const int a0 = lane * 8;

    // phase 1: attention energies for both g
    #pragma unroll
    for (int g = 0; g < 2; ++g) {
        const _Float16* sp = Yh + (long long)(g * B_ + b) * 2048;
        const f16x8 spv = *(const f16x8*)(sp + a0);
        const float* wvg = wv + g * 512;
        const f32x4 wv0 = *(const f32x4*)(wvg + a0);
        const f32x4 wv1 = *(const f32x4*)(wvg + a0 + 4);
        const _Float16* xpb = xpj + (long long)(g * B_ + b) * 25 * 512;
        for (int l = w; l < 25; l += 4) {
            const f16x8 xv = *(const f16x8*)(xpb + l * 512 + a0);
            float part = 0.0f;
            #pragma unroll
            for (int i = 0; i < 4; ++i) {
                part += fast_tanh((float)spv[i]     + (float)xv[i])     * wv0[i];
                part += fast_tanh((float)spv[4 + i] + (float)xv[4 + i]) * wv1[i];
            }
            #pragma unroll
            for (int off = 32; off > 0; off >>= 1) part += __shfl_xor(part, off);
            if (lane == 0) eL[g][l] = part;     // wvb cancels in softmax
        }
    }
    __syncthreads();

    // phase 2: per-thread softmax weights (statically indexed arrays)
    float al0[25], al1[25];
    float m0 = -1e30f, m1 = -1e30f;
    #pragma unroll
    for (int l = 0; l < 25; ++l) { m0 = fmaxf(m0, eL[0][l]); m1 = fmaxf(m1, eL[1][l]); }
    float ss0 = 0.0f, ss1 = 0.0f;
    #pragma unroll
    for (int l = 0; l < 25; ++l) {
        al0[l] = __expf(eL[0][l] - m0); ss0 += al0[l];
        al1[l] = __expf(eL[1][l] - m1); ss1 += al1[l];
    }
    const float inv0 = 1.0f / ss0, inv1 = 1.0f / ss1;

    // phase 3: ctx partials; wave w accumulates its rows over full 512 cols
    float c0[8], c1[8];
    #pragma unroll
    for (int j = 0; j < 8; ++j) { c0[j] = 0.0f; c1[j] = 0.0f; }
    const _Float16* xb = xh + (long long)b * 25 * 512;
    #pragma unroll
    for (int l = 0; l < 25; ++l) {
        if ((l & 3) == w) {                    // wave-uniform guard, l stays static
            const f16x8 xv = *(const f16x8*)(xb + l * 512 + a0);
            #pragma unroll
            for (int j = 0; j < 8; ++j) {
                const float xf = (float)xv[j];
                c0[j] += al0[l] * xf;
                c1[j] += al1[l] * xf;
            }
        }
    }
    f32x4 p;
    #pragma unroll
    for (int h = 0; h < 2; ++h) {
        #pragma unroll
        for (int i = 0; i < 4; ++i) p[i] = c0[h * 4 + i] * inv0;
        *(f32x4*)&red[0][w][a0 + h * 4] = p;
        #pragma unroll
        for (int i = 0; i < 4; ++i) p[i] = c1[h * 4 + i] * inv1;
        *(f32x4*)&red[1][w][a0 + h * 4] = p;
    }
    __syncthreads();

    // phase 4: cross-wave reduce + fp16 store, 2 cols/thread per g
    const int c = tid * 2;
    f32x2 s0 = {0.0f, 0.0f}, s1 = {0.0f, 0.0f};
    #pragma unroll
    for (int ww = 0; ww < 4; ++ww) {
        s0 += *(const f32x2*)&red[0][ww][c];
        s1 += *(const f32x2*)&red[1][ww][c];
    }
    f16x2 o0, o1;
    o0[0] = (_Float16)s0[0]; o0[1] = (_Float16)s0[1];
    o1[0] = (_Float16)s1[0]; o1[1] = (_Float16)s1[1];
    *(f16x2*)(ctxh + (long long)b * 512 + c) = o0;
    *(f16x2*)(ctxh + (long long)(B_ + b) * 512 + c) = o1;
}

// ---------------- GRU gate + state update (2 cols per thread) ----------------
__global__ void k_gate(const _Float16* __restrict__ Yh,  // gh = cols 512..2047
                       const _Float16* __restrict__ Y2h, // ctxProj [2][B][1536]
                       const float* __restrict__ eW,     // embW [2][128][1536] (incl bih)
                       const int* __restrict__ tgt,      // [2][B][25]
                       float* __restrict__ s32, _Float16* __restrict__ sh, int t)
{
    const int idx = blockIdx.x * 256 + threadIdx.x;
    if (idx >= 2 * B_ * 256) return;
    const int jp = (idx & 255) * 2;
    const int b  = (idx >> 8) & (B_ - 1);
    const int g  = idx >> 19;
    const int y  = (t == 0) ? CL_ : tgt[(g * B_ + b) * T_ + t - 1];
    const float*    ew = eW  + (long long)(g * 128 + y) * 1536;
    const _Float16* y2 = Y2h + (long long)(g * B_ + b) * 1536;
    const _Float16* yy = Yh  + (long long)(g * B_ + b) * 2048;
    const f32x2 ewr = *(const f32x2*)(ew + jp);
    const f32x2 ewz = *(const f32x2*)(ew + 512 + jp);
    const f32x2 ewn = *(const f32x2*)(ew + 1024 + jp);
    const f16x2 y2r = *(const f16x2*)(y2 + jp);
    const f16x2 y2z = *(const f16x2*)(y2 + 512 + jp);
    const f16x2 y2n = *(const f16x2*)(y2 + 1024 + jp);
    const f16x2 ghr = *(const f16x2*)(yy + 512 + jp);
    const f16x2 ghz = *(const f16x2*)(yy + 1024 + jp);
    const f16x2 ghn = *(const f16x2*)(yy + 1536 + jp);
    const long long si = (long long)(g * B_ + b) * 512 + jp;
    const f32x2 so = *(const f32x2*)(s32 + si);
    f32x2 sn;
    f16x2 snh;
    #pragma unroll
    for (int i = 0; i < 2; ++i) {
        const float r  = fast_sigm(ewr[i] + (float)y2r[i] + (float)ghr[i]);
        const float z  = fast_sigm(ewz[i] + (float)y2z[i] + (float)ghz[i]);
        const float nn = fast_tanh(ewn[i] + (float)y2n[i] + r * (float)ghn[i]);
        sn[i]  = (1.0f - z) * nn + z * so[i];
        snh[i] = (_Float16)sn[i];
    }
    *(f32x2*)(s32 + si) = sn;
    *(f16x2*)(sh + si) = snh;
}

// ---------------- launcher ----------------
extern "C" void kernel_launch(void* const* d_in, const int* in_sizes, int n_in,
                              void* d_out, int out_size, void* d_ws, size_t ws_size,
                              hipStream_t stream)
{
    (void)in_sizes; (void)n_in; (void)out_size;
    const float* x   = (const float*)d_in[0];
    const int*   tgt = (const int*)d_in[1];
    const float* Wx  = (const float*)d_in[2];
    const float* bx  = (const float*)d_in[3];
    const float* Wsm = (const float*)d_in[4];
    const float* bs  = (const float*)d_in[5];
    const float* wv  = (const float*)d_in[6];
    // d_in[7] = wvb: cancels in softmax, unused
    const float* emb = (const float*)d_in[8];
    const float* Wih = (const float*)d_in[9];
    const float* bih = (const float*)d_in[10];
    const float* Whh = (const float*)d_in[11];
    const float* bhh = (const float*)d_in[12];
    const float* Wfc = (const float*)d_in[13];
    const float* bfc = (const float*)d_in[14];
    float* out = (float*)d_out;

    char* base = (char*)d_ws;
    size_t off = 0;
    auto alloc = [&](size_t bytes) -> void* {
        void* r = base + off;
        off = (off + bytes + 255) & ~(size_t)255;
        return r;
    };
    _Float16* xh   = (_Float16*)alloc((size_t)B_ * T_ * 512 * 2);
    _Float16* xpj  = (_Float16*)alloc((size_t)2 * B_ * T_ * 512 * 2);
    _Float16* w1   = (_Float16*)alloc((size_t)2 * 2176 * 512 * 2);
    _Float16* w2   = (_Float16*)alloc((size_t)2 * 1536 * 512 * 2);
    _Float16* w2e  = (_Float16*)alloc((size_t)2 * 1536 * 512 * 2);
    _Float16* wx   = (_Float16*)alloc((size_t)2 * 512 * 512 * 2);
    _Float16* embh = (_Float16*)alloc((size_t)2 * 128 * 512 * 2);
    float*    b1   = (float*)alloc((size_t)2 * 2176 * 4);
    float*    eW   = (float*)alloc((size_t)2 * 128 * 1536 * 4);
    float*    s32  = (float*)alloc((size_t)2 * B_ * 512 * 4);
    _Float16* sh   = (_Float16*)alloc((size_t)2 * B_ * 512 * 2);
    _Float16* ctx  = (_Float16*)alloc((size_t)2 * B_ * 512 * 2);
    _Float16* Yh   = (_Float16*)alloc((size_t)2 * B_ * 2048 * 2);
    _Float16* Y2h  = (_Float16*)alloc((size_t)2 * B_ * 1536 * 2);
    if (off > ws_size) return;

    hipMemsetAsync(s32, 0, (size_t)2 * B_ * 512 * 4, stream);
    hipMemsetAsync(sh,  0, (size_t)2 * B_ * 512 * 2, stream);

    k_convx   <<<12800, 256, 0, stream>>>(x, xh, (B_ * T_ * 512) / 8);
    k_pack_w1 <<<1088, 256, 0, stream>>>(Wsm, Whh, Wfc, bs, bhh, bfc, w1, b1);
    k_pack_w2 <<<768, 256, 0, stream>>>(Wih, w2, w2e);
    k_pack_wx <<<256, 256, 0, stream>>>(Wx, wx);
    k_pack_emb<<<64, 256, 0, stream>>>(emb, embh);

    // embW = embh @ w2e^T + bih : M=128, N=1536
    gemm_bt<<<dim3(12, 1, 2), 256, 0, stream>>>(
        embh, 128ll * 512, w2e, 1536ll * 512, eW, nullptr,
        128ll * 1536, 1536, bih, 1536, 0, 1 << 30, nullptr, 0, 0);

    // xProj[g] = xh @ WxBt[g] + bx[g]  (fp16 out), M=51200, N=512
    gemm_bt<<<dim3(4, 400, 2), 256, 0, stream>>>(
        xh, 0ll, wx, 512ll * 512, nullptr, xpj, (long long)B_ * T_ * 512, 512,
        bx, 512, 0, 1 << 30, nullptr, 0, 0);

    for (int t = 0; t < T_; ++t) {
        // Y = s @ [Ws | Whh.T | Wfc.T] + [bs|bhh|bfc]; logits cols -> out[t-1]
        gemm_bt<<<dim3(t > 0 ? 17 : 16, 16, 2), 256, 0, stream>>>(
            sh, (long long)B_ * 512, w1, 2176ll * 512, nullptr, Yh,
            (long long)B_ * 2048, 2048, b1, 2176, 0, 2048,
            t > 0 ? out + (long long)(t - 1) * CL_ : nullptr, CL_, T_ * CL_);
        k_att<<<dim3(B_, 1, 1), 256, 0, stream>>>(Yh, xpj, xh, wv, ctx);
        // ctxProj = ctx @ WihCtx.T  (bih folded into embW)
        gemm_bt<<<dim3(12, 16, 2), 256, 0, stream>>>(
            ctx, (long long)B_ * 512, w2, 1536ll * 512, nullptr, Y2h,
            (long long)B_ * 1536, 1536, nullptr, 0, 0, 1 << 30, nullptr, 0, 0);
        k_gate<<<4096, 256, 0, stream>>>(Yh, Y2h, eW, tgt, s32, sh, t);
    }
    // final logits (step T-1) from s_T
    gemm_bt<<<dim3(1, 16, 2), 256, 0, stream>>>(
        sh, (long long)B_ * 512, w1, 2176ll * 512, nullptr, Yh,
        (long long)B_ * 2048, 2048, b1, 2176, 16, 2048,
        out + 24ll * CL_, CL_, T_ * CL_);
}